// Round 1
// 882.581 us; speedup vs baseline: 1.5628x; 1.5628x over previous
//
#include <hip/hip_runtime.h>

#define NB   128
#define NIN  1024
#define NH   1024
#define BETAF 0.95f
#define PIF  3.14159265358979f

// d_out flat layout (elements), return order:
// spk(B*NH), mem_new(B*NH), loss_mean(1), spk_trace_new(B*NH),
// inp_trace_new(B*NIN), current_dW_new(B*NH*NIN), sample_loss_new(B)
#define OFF_SPK    0
#define OFF_MEM    (NB*NH)
#define OFF_LOSS   (2*NB*NH)
#define OFF_SPKTR  (2*NB*NH + 1)
#define OFF_INPTR  (3*NB*NH + 1)
#define OFF_DW     (3*NB*NH + NB*NIN + 1)
#define OFF_SLOSS  (OFF_DW + (size_t)NB*NH*NIN)

typedef float f4 __attribute__((ext_vector_type(4)));

// ---------------------------------------------------------------------------
// Kernel 1: inp_trace_new = beta*inp_trace + inp ; init loss accumulator
// ---------------------------------------------------------------------------
__global__ __launch_bounds__(256) void k_trace(
    const float* __restrict__ inp, const float* __restrict__ inp_trace,
    float* __restrict__ out)
{
    int t = blockIdx.x * 256 + threadIdx.x;
    out[OFF_INPTR + t] = BETAF * inp_trace[t] + inp[t];
    if (t == 0)
        out[OFF_LOSS] = 0.0f;
}

// ---------------------------------------------------------------------------
// Kernel 2: cur = inp @ W^T, leaky step, spk, spk_trace.
// One wave (64 lanes) per (b,h). Block = 4 waves = 4 h's, one b.
// fp64 accumulation to minimize threshold-boundary flips vs np reference.
// NO atomics here — the previous version's 2 device-scope atomics/block
// (32768 blocks, one shared address) serialized at the TCC = the 421 us.
// ---------------------------------------------------------------------------
__global__ __launch_bounds__(256) void k_leaky(
    const float* __restrict__ inp, const float* __restrict__ W,
    const float* __restrict__ mem, const float* __restrict__ spk_trace,
    float* __restrict__ out)
{
    const int b    = blockIdx.y;
    const int wave = threadIdx.x >> 6;
    const int lane = threadIdx.x & 63;
    const int h    = blockIdx.x * 4 + wave;

    const float* ir = inp + b * NIN;
    const float* wr = W   + h * NIN;

    double acc = 0.0;
    #pragma unroll
    for (int i = 0; i < NIN; i += 64)
        acc += (double)ir[i + lane] * (double)wr[i + lane];

    #pragma unroll
    for (int off = 32; off > 0; off >>= 1)
        acc += __shfl_down(acc, off, 64);

    if (lane == 0) {
        const int idx = b * NH + h;
        float cur = (float)acc;
        float m   = mem[idx];
        float mn  = BETAF * m + cur - (m > 1.0f ? 1.0f : 0.0f);
        float spk = (mn > 1.0f) ? 1.0f : 0.0f;
        out[OFF_SPK   + idx] = spk;
        out[OFF_MEM   + idx] = mn;
        out[OFF_SPKTR + idx] = spk_trace[idx] + spk * 0.01f;
    }
}

// ---------------------------------------------------------------------------
// Kernel 2b: per-sample loss. One block per b; reads spk (just written) and
// prev_spk_trace (1 MB total), tree-reduces, writes sample_loss_new[b]
// directly and does exactly NB=128 atomics to the loss mean. ~3 us.
// ---------------------------------------------------------------------------
__global__ __launch_bounds__(256) void k_loss(
    const float* __restrict__ pst, const float* __restrict__ sample_loss,
    const int* __restrict__ bf_p, float* __restrict__ out)
{
    const int b = blockIdx.x;
    const int t = threadIdx.x;
    const float* spk = out + OFF_SPK + b * NH;
    const float* pr  = pst + b * NH;

    float s = 0.0f;
    #pragma unroll
    for (int k = 0; k < 4; ++k) {
        int h = t + k * 256;
        s += spk[h] * pr[h];
    }
    #pragma unroll
    for (int off = 32; off > 0; off >>= 1)
        s += __shfl_down(s, off, 64);

    __shared__ float sl[4];
    if ((t & 63) == 0) sl[t >> 6] = s;
    __syncthreads();
    if (t == 0) {
        float bf = (float)(*bf_p);
        float c  = -bf * (sl[0] + sl[1] + sl[2] + sl[3]);
        out[OFF_SLOSS + b] = sample_loss[b] + c;
        atomicAdd(&out[OFF_LOSS], c * (1.0f / NB));
    }
}

// ---------------------------------------------------------------------------
// Kernel 3 (the 1.07 GB streaming kernel):
//   dW_new[b,h,i] = dW[b,h,i] + bf * pre[b,h] * itn[b,i]
// pre recomputed on the fly from mem_new + prev_spk_trace (broadcast L1 hits).
// Non-temporal dwordx4 on the dW stream (read-once/write-once) so the 1 GB
// stream doesn't evict the reused itn/memn/pst lines from L2.
// od/itn are element-odd (4B-aligned): multi-dword global ops only require
// dword alignment on gfx9-lineage, so dwordx4 at +4B is HW-legal.
// ---------------------------------------------------------------------------
__global__ __launch_bounds__(256) void k_dw(
    const float* __restrict__ dW, const float* __restrict__ pst,
    const int* __restrict__ bf_p, float* __restrict__ out)
{
    const float* __restrict__ itn  = out + OFF_INPTR;
    const float* __restrict__ memn = out + OFF_MEM;
    float* __restrict__ od = out + OFF_DW;

    int t = blockIdx.x * 256 + threadIdx.x;   // t in [0, 2^25)
    int j = t << 2;                           // element index, < 2^27
    int b  = j >> 20;                         // NH*NIN = 2^20
    int h  = (j >> 10) & (NH - 1);
    int i  = j & (NIN - 1);
    int bh = (b << 10) + h;

    float mn = memn[bh];
    float x  = mn - 1.0f;
    float px = PIF * x;
    float p  = (float)(*bf_p) * pst[bh] / (PIF * (1.0f + px * px));

    f4 it = *(const f4*)(itn + (b << 10) + i);          // L1/L2 hit (reused per b)
    f4 d  = __builtin_nontemporal_load((const f4*)(dW + j));

    f4 r;
    r.x = d.x + p * it.x;
    r.y = d.y + p * it.y;
    r.z = d.z + p * it.z;
    r.w = d.w + p * it.w;
    __builtin_nontemporal_store(r, (f4*)(od + j));
}

extern "C" void kernel_launch(void* const* d_in, const int* in_sizes, int n_in,
                              void* d_out, int out_size, void* d_ws, size_t ws_size,
                              hipStream_t stream)
{
    const float* inp        = (const float*)d_in[0];
    const float* W          = (const float*)d_in[1];
    const float* mem        = (const float*)d_in[2];
    const float* spk_trace  = (const float*)d_in[3];
    const float* inp_trace  = (const float*)d_in[4];
    const float* pst        = (const float*)d_in[5];
    const float* dW         = (const float*)d_in[6];
    const float* sloss      = (const float*)d_in[7];
    const int*   bf_p       = (const int*)  d_in[8];
    float* out = (float*)d_out;

    // 1) input trace + loss-mean init
    k_trace<<<dim3((NB * NIN) / 256), dim3(256), 0, stream>>>(inp, inp_trace, out);

    // 2) matmul + leaky step: grid (NH/4, B), 4 waves/block, no atomics
    k_leaky<<<dim3(NH / 4, NB), dim3(256), 0, stream>>>(
        inp, W, mem, spk_trace, out);

    // 2b) loss reduction: 128 blocks, 128 total atomics
    k_loss<<<dim3(NB), dim3(256), 0, stream>>>(pst, sloss, bf_p, out);

    // 3) dW streaming update: 2^25 groups of 4 elements
    k_dw<<<dim3((NB * NH * NIN / 4) / 256), dim3(256), 0, stream>>>(dW, pst, bf_p, out);
}